// Round 1
// baseline (237.205 us; speedup 1.0000x reference)
//
#include <hip/hip_runtime.h>
#include <cstdint>
#include <cstddef>

#define EPS 1e-8f

// Fixed problem instance
#define Bsz 8
#define Nn  5
#define Kk  5
#define Qq  4
#define Ll  128
#define Ff  768
#define NQ  (Nn*Qq)          // 20
#define Tt  (2*Nn+1)         // 11
#define KL  (Kk*Ll)          // 640
#define ROWS_PER_B (NQ*Ll)   // 2560
#define NROWS (Bsz*ROWS_PER_B) // 20480
#define F4  (Ff/4)           // 192 float4 per row

// ---------------- Stage 1: per-chunk masked partial sums ----------------
// grid = (B*N*CH) blocks, 256 threads. Each thread owns f = tid, tid+256, tid+512.
__global__ __launch_bounds__(256) void stage1_partials(
    const float* __restrict__ sup,      // [B][N][K][L][F]
    const int*   __restrict__ Bm,       // [B][N][K][L]
    const int*   __restrict__ Im,
    float* __restrict__ part,           // [nblk][3][F]
    float* __restrict__ cntB,           // [nblk]
    float* __restrict__ cntI,           // [nblk]
    int CH, int CHUNK)
{
    int blk  = blockIdx.x;
    int bn   = blk / CH;
    int ch   = blk - bn * CH;
    int pos0 = ch * CHUNK;
    int tid  = threadIdx.x;

    const float* sp = sup + ((size_t)bn * KL + pos0) * Ff;
    const int*   bp = Bm + bn * KL + pos0;
    const int*   ip = Im + bn * KL + pos0;

    __shared__ float smB[KL];
    __shared__ float smI[KL];
    for (int p = tid; p < CHUNK; p += 256) {
        smB[p] = (float)bp[p];
        smI[p] = (float)ip[p];
    }
    __syncthreads();

    float aB0=0,aB1=0,aB2=0, aI0=0,aI1=0,aI2=0, aO0=0,aO1=0,aO2=0;
    const float* r = sp + tid;
    for (int p = 0; p < CHUNK; ++p, r += Ff) {
        float mb = smB[p], mi = smI[p];
        float mo = 1.0f - mb - mi;
        float v0 = r[0], v1 = r[256], v2 = r[512];
        aB0 = fmaf(mb, v0, aB0); aB1 = fmaf(mb, v1, aB1); aB2 = fmaf(mb, v2, aB2);
        aI0 = fmaf(mi, v0, aI0); aI1 = fmaf(mi, v1, aI1); aI2 = fmaf(mi, v2, aI2);
        aO0 = fmaf(mo, v0, aO0); aO1 = fmaf(mo, v1, aO1); aO2 = fmaf(mo, v2, aO2);
    }
    float* o = part + (size_t)blk * (3 * Ff);
    o[tid]          = aB0; o[tid + 256]          = aB1; o[tid + 512]          = aB2;
    o[Ff + tid]     = aI0; o[Ff + tid + 256]     = aI1; o[Ff + tid + 512]     = aI2;
    o[2*Ff + tid]   = aO0; o[2*Ff + tid + 256]   = aO1; o[2*Ff + tid + 512]   = aO2;

    if (tid == 0) { float c = 0; for (int p = 0; p < CHUNK; ++p) c += smB[p]; cntB[blk] = c; }
    if (tid == 1) { float c = 0; for (int p = 0; p < CHUNK; ++p) c += smI[p]; cntI[blk] = c; }
}

// ---------------- Stage 2: finalize prototypes ----------------
// grid = B blocks, 768 threads (one per f).
__global__ void stage2_proto(
    const float* __restrict__ part,
    const float* __restrict__ cntB,
    const float* __restrict__ cntI,
    float* __restrict__ proto,          // [B][T][F]
    int CH)
{
    int b = blockIdx.x;
    int f = threadIdx.x;

    float sumO = 0.0f, cntO = 0.0f;
    for (int n = 0; n < Nn; ++n) {
        int bn = b * Nn + n;
        float sB = 0, sI = 0, sO = 0, cB = 0, cI = 0;
        for (int ch = 0; ch < CH; ++ch) {
            const float* p = part + (size_t)(bn * CH + ch) * (3 * Ff);
            sB += p[f];
            sI += p[Ff + f];
            sO += p[2 * Ff + f];
            cB += cntB[bn * CH + ch];
            cI += cntI[bn * CH + ch];
        }
        proto[((size_t)b * Tt + (1 + 2 * n)) * Ff + f] = sB / (cB + EPS);
        proto[((size_t)b * Tt + (2 + 2 * n)) * Ff + f] = sI / (cI + EPS);
        sumO += sO;
        cntO += (float)KL - cB - cI;
    }
    proto[(size_t)b * Tt * Ff + f] = sumO / (cntO + EPS);
}

// ---------------- Stage 3: logits + argmax + log-softmax NLL ----------------
// grid = B * 80 blocks, 256 threads (4 waves); each wave handles 8 rows.
#define BLOCKS_PER_B 80
#define ROWS_PER_WAVE 8

__global__ __launch_bounds__(256) void stage3_logits(
    const float* __restrict__ query,    // [B][2560][F]
    const float* __restrict__ proto,    // [B][T][F]
    const int*   __restrict__ label,    // [B*2560]
    float* __restrict__ out_logits,     // [NROWS][T]
    float* __restrict__ out_pred,       // [NROWS]
    float* __restrict__ loss_out)       // [1]
{
    __shared__ float4 sp[Tt * F4];      // 11*192*16 = 33792 B
    __shared__ float sLoss;

    int b  = blockIdx.x / BLOCKS_PER_B;
    int rg = blockIdx.x - b * BLOCKS_PER_B;

    if (threadIdx.x == 0) sLoss = 0.0f;
    const float4* pg = (const float4*)(proto + (size_t)b * Tt * Ff);
    for (int i = threadIdx.x; i < Tt * F4; i += 256) sp[i] = pg[i];
    __syncthreads();

    int wave = threadIdx.x >> 6;
    int lane = threadIdx.x & 63;
    int row0 = rg * (4 * ROWS_PER_WAVE) + wave * ROWS_PER_WAVE;  // within-b row

    float wloss = 0.0f;

    for (int r = 0; r < ROWS_PER_WAVE; ++r) {
        int row = row0 + r;
        size_t grow = (size_t)b * ROWS_PER_B + row;
        const float4* q = (const float4*)(query + grow * Ff);
        float4 q0 = q[lane], q1 = q[64 + lane], q2 = q[128 + lane];
        int lab = label[grow];

        float m = -INFINITY, s = 0.0f, labv = 0.0f, bestv = -INFINITY;
        int bestt = 0;
        float myLogit = 0.0f;

        for (int t = 0; t < Tt; ++t) {
            const float4* pv = &sp[t * F4];
            float4 p0 = pv[lane], p1 = pv[64 + lane], p2 = pv[128 + lane];
            float d = q0.x*p0.x + q0.y*p0.y + q0.z*p0.z + q0.w*p0.w
                    + q1.x*p1.x + q1.y*p1.y + q1.z*p1.z + q1.w*p1.w
                    + q2.x*p2.x + q2.y*p2.y + q2.z*p2.z + q2.w*p2.w;
            #pragma unroll
            for (int off = 32; off > 0; off >>= 1) d += __shfl_xor(d, off, 64);
            // d is now wave-uniform (full row dot)
            if (t == lane) myLogit = d;
            if (d > bestv) { bestv = d; bestt = t; }   // strict > keeps first max
            float mnew = fmaxf(m, d);
            s = s * __expf(m - mnew) + __expf(d - mnew);
            m = mnew;
            if (t == lab) labv = d;
        }

        if (lane < Tt) out_logits[grow * Tt + lane] = myLogit;
        if (lane == 0) out_pred[grow] = (float)bestt;
        wloss += (m + __logf(s)) - labv;   // -log_softmax[lab]
    }

    if (lane == 0) atomicAdd(&sLoss, wloss);
    __syncthreads();
    if (threadIdx.x == 0) atomicAdd(loss_out, sLoss * (1.0f / (float)NROWS));
}

// ---------------- Host launch ----------------
extern "C" void kernel_launch(void* const* d_in, const int* in_sizes, int n_in,
                              void* d_out, int out_size, void* d_ws, size_t ws_size,
                              hipStream_t stream) {
    const float* sup   = (const float*)d_in[0];
    const float* query = (const float*)d_in[1];
    const int*   Bm    = (const int*)d_in[2];
    const int*   Im    = (const int*)d_in[3];
    const int*   lab   = (const int*)d_in[4];
    // d_in[5..7] = N, K, Q scalars (device-resident) — dims hardcoded for this instance.

    // Pick chunk size (parallelism) that fits in workspace.
    int chunk_opts[4] = {32, 64, 128, 640};
    int CHUNK = 640;
    size_t protoFloats = (size_t)Bsz * Tt * Ff;   // 67584
    for (int i = 0; i < 4; ++i) {
        int c = chunk_opts[i];
        int nblk = (Bsz * Nn) * (KL / c);
        size_t protoOff = (((size_t)nblk * 3 * Ff + 2 * (size_t)nblk) + 3) & ~(size_t)3;
        size_t needBytes = (protoOff + protoFloats) * sizeof(float);
        if (needBytes <= ws_size) { CHUNK = c; break; }
    }
    int CH   = KL / CHUNK;
    int nblk = (Bsz * Nn) * CH;

    float* w     = (float*)d_ws;
    float* part  = w;
    float* cntB  = w + (size_t)nblk * 3 * Ff;
    float* cntI  = cntB + nblk;
    size_t protoOff = (((size_t)nblk * 3 * Ff + 2 * (size_t)nblk) + 3) & ~(size_t)3;
    float* proto = w + protoOff;

    float* loss_out   = (float*)d_out;
    float* out_logits = (float*)d_out + 1;
    float* out_pred   = (float*)d_out + 1 + (size_t)NROWS * Tt;

    // loss accumulator must start at 0 (d_out is poisoned before timed runs)
    hipMemsetAsync(d_out, 0, sizeof(float), stream);

    stage1_partials<<<nblk, 256, 0, stream>>>(sup, Bm, Im, part, cntB, cntI, CH, CHUNK);
    stage2_proto<<<Bsz, Ff, 0, stream>>>(part, cntB, cntI, proto, CH);
    stage3_logits<<<Bsz * BLOCKS_PER_B, 256, 0, stream>>>(query, proto, lab,
                                                          out_logits, out_pred, loss_out);
}

// Round 2
// 208.775 us; speedup vs baseline: 1.1362x; 1.1362x over previous
//
#include <hip/hip_runtime.h>
#include <cstdint>
#include <cstddef>

#define EPS 1e-8f

// Fixed problem instance
#define Bsz 8
#define Nn  5
#define Kk  5
#define Qq  4
#define Ll  128
#define Ff  768
#define NQ  (Nn*Qq)            // 20
#define Tt  (2*Nn+1)           // 11
#define KL  (Kk*Ll)            // 640
#define ROWS_PER_B (NQ*Ll)     // 2560
#define NROWS (Bsz*ROWS_PER_B) // 20480
#define F4  (Ff/4)             // 192 float4 per row
#define BN  (Bsz*Nn)           // 40

// Stage-1 chunking: fixed, small ws footprint via atomics.
#define S1_CHUNK 32
#define S1_CH    (KL / S1_CHUNK)   // 20 chunks -> 800 blocks

// ---------------- Stage 1: masked partial sums -> global atomic accum ----------------
// grid = BN * S1_CH = 800 blocks, 256 threads. Thread owns f = tid, tid+256, tid+512.
__global__ __launch_bounds__(256) void stage1_partials(
    const float* __restrict__ sup,      // [B][N][K][L][F]
    const int*   __restrict__ Bm,       // [B][N][K][L]
    const int*   __restrict__ Im,
    float* __restrict__ accum,          // [BN][3][F]  (zeroed)
    float* __restrict__ cnt)            // [BN][2]     (zeroed)
{
    int blk  = blockIdx.x;
    int bn   = blk / S1_CH;
    int ch   = blk - bn * S1_CH;
    int pos0 = ch * S1_CHUNK;
    int tid  = threadIdx.x;

    const float* sp = sup + ((size_t)bn * KL + pos0) * Ff;
    const int*   bp = Bm + bn * KL + pos0;
    const int*   ip = Im + bn * KL + pos0;

    __shared__ float smB[S1_CHUNK];
    __shared__ float smI[S1_CHUNK];
    if (tid < S1_CHUNK) {
        smB[tid] = (float)bp[tid];
        smI[tid] = (float)ip[tid];
    }
    __syncthreads();

    float aB0=0,aB1=0,aB2=0, aI0=0,aI1=0,aI2=0, aO0=0,aO1=0,aO2=0;
    const float* r = sp + tid;
    #pragma unroll 4
    for (int p = 0; p < S1_CHUNK; ++p, r += Ff) {
        float mb = smB[p], mi = smI[p];
        float mo = 1.0f - mb - mi;
        float v0 = r[0], v1 = r[256], v2 = r[512];
        aB0 = fmaf(mb, v0, aB0); aB1 = fmaf(mb, v1, aB1); aB2 = fmaf(mb, v2, aB2);
        aI0 = fmaf(mi, v0, aI0); aI1 = fmaf(mi, v1, aI1); aI2 = fmaf(mi, v2, aI2);
        aO0 = fmaf(mo, v0, aO0); aO1 = fmaf(mo, v1, aO1); aO2 = fmaf(mo, v2, aO2);
    }
    float* o = accum + (size_t)bn * (3 * Ff);
    atomicAdd(&o[tid],            aB0); atomicAdd(&o[tid + 256],          aB1); atomicAdd(&o[tid + 512],          aB2);
    atomicAdd(&o[Ff + tid],       aI0); atomicAdd(&o[Ff + tid + 256],     aI1); atomicAdd(&o[Ff + tid + 512],     aI2);
    atomicAdd(&o[2*Ff + tid],     aO0); atomicAdd(&o[2*Ff + tid + 256],   aO1); atomicAdd(&o[2*Ff + tid + 512],   aO2);

    if (tid == 0) { float c = 0; for (int p = 0; p < S1_CHUNK; ++p) c += smB[p]; atomicAdd(&cnt[bn*2],   c); }
    if (tid == 1) { float c = 0; for (int p = 0; p < S1_CHUNK; ++p) c += smI[p]; atomicAdd(&cnt[bn*2+1], c); }
}

// ---------------- Stage 2: finalize prototypes ----------------
// grid = B blocks, 768 threads (one per f). Reads 368 KB total — trivial.
__global__ void stage2_proto(
    const float* __restrict__ accum,    // [BN][3][F]
    const float* __restrict__ cnt,      // [BN][2]
    float* __restrict__ proto)          // [B][T][F]
{
    int b = blockIdx.x;
    int f = threadIdx.x;

    float sumO = 0.0f, cntO = 0.0f;
    #pragma unroll
    for (int n = 0; n < Nn; ++n) {
        int bn = b * Nn + n;
        const float* a = accum + (size_t)bn * (3 * Ff);
        float cB = cnt[bn*2], cI = cnt[bn*2+1];
        proto[((size_t)b * Tt + (1 + 2 * n)) * Ff + f] = a[f]        / (cB + EPS);
        proto[((size_t)b * Tt + (2 + 2 * n)) * Ff + f] = a[Ff + f]   / (cI + EPS);
        sumO += a[2*Ff + f];
        cntO += (float)KL - cB - cI;
    }
    proto[(size_t)b * Tt * Ff + f] = sumO / (cntO + EPS);
}

// ---------------- Stage 3: logits + argmax + log-softmax NLL ----------------
// grid = B * 160 blocks, 256 threads (4 waves); each wave handles 4 rows.
// Proto held in registers (33 float4/lane); reduction = 6-deep butterfly over
// 11 INDEPENDENT accumulators (ILP-pipelined), then lane-local softmax.
#define S3_BLOCKS_PER_B 160
#define S3_ROWS_PER_WAVE 4

__global__ __launch_bounds__(256) void stage3_logits(
    const float* __restrict__ query,    // [B][2560][F]
    const float* __restrict__ proto,    // [B][T][F]
    const int*   __restrict__ label,    // [B*2560]
    float* __restrict__ out_logits,     // [NROWS][T]
    float* __restrict__ out_pred,       // [NROWS]
    float* __restrict__ loss_out)       // [1]
{
    __shared__ float sLoss;

    int b  = blockIdx.x / S3_BLOCKS_PER_B;
    int rg = blockIdx.x - b * S3_BLOCKS_PER_B;
    int wave = threadIdx.x >> 6;
    int lane = threadIdx.x & 63;

    if (threadIdx.x == 0) sLoss = 0.0f;
    __syncthreads();

    // Load this batch's full prototype set into registers (coalesced).
    const float4* pg = (const float4*)(proto + (size_t)b * Tt * Ff);
    float4 P[Tt][3];
    #pragma unroll
    for (int t = 0; t < Tt; ++t) {
        P[t][0] = pg[t * F4 + lane];
        P[t][1] = pg[t * F4 + 64 + lane];
        P[t][2] = pg[t * F4 + 128 + lane];
    }

    int row0 = rg * (4 * S3_ROWS_PER_WAVE) + wave * S3_ROWS_PER_WAVE;
    float wloss = 0.0f;

    for (int r = 0; r < S3_ROWS_PER_WAVE; ++r) {
        size_t grow = (size_t)b * ROWS_PER_B + row0 + r;
        const float4* q = (const float4*)(query + grow * Ff);
        float4 q0 = q[lane], q1 = q[64 + lane], q2 = q[128 + lane];
        int lab = label[grow];

        float acc[Tt];
        #pragma unroll
        for (int t = 0; t < Tt; ++t) {
            float d;
            d = q0.x * P[t][0].x;
            d = fmaf(q0.y, P[t][0].y, d); d = fmaf(q0.z, P[t][0].z, d); d = fmaf(q0.w, P[t][0].w, d);
            d = fmaf(q1.x, P[t][1].x, d); d = fmaf(q1.y, P[t][1].y, d);
            d = fmaf(q1.z, P[t][1].z, d); d = fmaf(q1.w, P[t][1].w, d);
            d = fmaf(q2.x, P[t][2].x, d); d = fmaf(q2.y, P[t][2].y, d);
            d = fmaf(q2.z, P[t][2].z, d); d = fmaf(q2.w, P[t][2].w, d);
            acc[t] = d;
        }
        // Butterfly-reduce all 11 accumulators; chains are independent -> ILP.
        #pragma unroll
        for (int off = 32; off > 0; off >>= 1) {
            #pragma unroll
            for (int t = 0; t < Tt; ++t) acc[t] += __shfl_xor(acc[t], off, 64);
        }
        // Every lane now holds the full 11-logit row.
        float m = acc[0]; int bt = 0;
        #pragma unroll
        for (int t = 1; t < Tt; ++t) if (acc[t] > m) { m = acc[t]; bt = t; }  // first-max
        float s = 0.0f;
        #pragma unroll
        for (int t = 0; t < Tt; ++t) s += __expf(acc[t] - m);
        float labv = acc[0];
        #pragma unroll
        for (int t = 1; t < Tt; ++t) labv = (lab == t) ? acc[t] : labv;
        float myv = acc[0];
        #pragma unroll
        for (int t = 1; t < Tt; ++t) myv = (lane == t) ? acc[t] : myv;

        if (lane < Tt) out_logits[grow * Tt + lane] = myv;
        if (lane == 0) out_pred[grow] = (float)bt;
        wloss += (m + __logf(s)) - labv;
    }

    if (lane == 0) atomicAdd(&sLoss, wloss);
    __syncthreads();
    if (threadIdx.x == 0) atomicAdd(loss_out, sLoss * (1.0f / (float)NROWS));
}

// ---------------- Host launch ----------------
extern "C" void kernel_launch(void* const* d_in, const int* in_sizes, int n_in,
                              void* d_out, int out_size, void* d_ws, size_t ws_size,
                              hipStream_t stream) {
    const float* sup   = (const float*)d_in[0];
    const float* query = (const float*)d_in[1];
    const int*   Bm    = (const int*)d_in[2];
    const int*   Im    = (const int*)d_in[3];
    const int*   lab   = (const int*)d_in[4];

    // ws layout: accum [BN][3][F] | cnt [BN][2] | proto [B][T][F]
    float* w     = (float*)d_ws;
    float* accum = w;                                   // 40*3*768 = 92160 floats
    float* cnt   = accum + (size_t)BN * 3 * Ff;         // 80 floats
    float* proto = cnt + 2 * BN;                        // 67584 floats
    size_t zeroBytes = ((size_t)BN * 3 * Ff + 2 * BN) * sizeof(float);  // ~369 KB

    float* loss_out   = (float*)d_out;
    float* out_logits = (float*)d_out + 1;
    float* out_pred   = (float*)d_out + 1 + (size_t)NROWS * Tt;

    hipMemsetAsync(d_ws, 0, zeroBytes, stream);
    hipMemsetAsync(d_out, 0, sizeof(float), stream);

    stage1_partials<<<BN * S1_CH, 256, 0, stream>>>(sup, Bm, Im, accum, cnt);
    stage2_proto<<<Bsz, Ff, 0, stream>>>(accum, cnt, proto);
    stage3_logits<<<Bsz * S3_BLOCKS_PER_B, 256, 0, stream>>>(query, proto, lab,
                                                             out_logits, out_pred, loss_out);
}